// Round 6
// baseline (10974.999 us; speedup 1.0000x reference)
//
#include <hip/hip_runtime.h>

#define B_  16
#define H_  1024
#define E_  512
#define V_  32000
#define S_  128
#define G4  4096   // 4*H

// ---------------- embedding gather (float4 over E) ----------------
__global__ __launch_bounds__(256) void embed_kernel(
    const int* __restrict__ idx, const float* __restrict__ emb,
    float* __restrict__ out, int nrows, int TU, int TS)
{
    const int E4 = E_ / 4;
    int i = blockIdx.x * 256 + threadIdx.x;     // over nrows*E4 float4s
    if (i >= nrows * E4) return;
    int r = i / E4, e = i - r * E4;
    int b = r / TU, tl = r - b * TU;
    int tok = idx[b * TS + tl];
    reinterpret_cast<float4*>(out)[i] =
        reinterpret_cast<const float4*>(emb)[(long)tok * E4 + e];
}

// ---------------- transpose: out[c][r] = in[r][c] ----------------
__global__ __launch_bounds__(256) void transpose_kernel(
    const float* __restrict__ in, float* __restrict__ out, int R, int C)
{
    __shared__ float tile[32][33];
    int r0 = blockIdx.y * 32, c0 = blockIdx.x * 32;
    int tx = threadIdx.x & 31, ty = threadIdx.x >> 5;   // 256 thr: ty 0..7
    for (int i = ty; i < 32; i += 8) {
        int r = r0 + i, c = c0 + tx;
        tile[i][tx] = (r < R && c < C) ? in[(long)r * C + c] : 0.f;
    }
    __syncthreads();
    for (int i = ty; i < 32; i += 8) {
        int c = c0 + i, r = r0 + tx;
        if (c < C && r < R) out[(long)c * R + r] = tile[tx][i];
    }
}

// ---------------- f32 tiled GEMM: C[M,N] = A[M,K] @ W[N,K]^T + bias ----------------
// fc_mode: row r -> output row (b*128 + t + 1) with r = b*127 + t  (decoder->logits remap)
#define TM 128
#define TN 128
#define TKg 16
__global__ __launch_bounds__(256) void gemm_bias_kernel(
    const float* __restrict__ A, const float* __restrict__ W,
    const float* __restrict__ bias, float* __restrict__ C,
    int M, int N, int K, int fc_mode)
{
    __shared__ float As[TKg][TM + 4];
    __shared__ float Ws[TKg][TN + 4];
    int m0 = blockIdx.y * TM, n0 = blockIdx.x * TN;
    int t = threadIdx.x;
    int tm = t >> 4, tn = t & 15;
    float acc[8][8] = {};
    for (int k0 = 0; k0 < K; k0 += TKg) {
        #pragma unroll
        for (int rep = 0; rep < 2; rep++) {
            int fi = t + rep * 256;             // 0..511 float4 slots (128 rows x 4)
            int row = fi >> 2, kq = fi & 3;
            float4 v = make_float4(0.f, 0.f, 0.f, 0.f);
            if (m0 + row < M)
                v = *reinterpret_cast<const float4*>(&A[(long)(m0 + row) * K + k0 + kq * 4]);
            As[kq * 4 + 0][row] = v.x; As[kq * 4 + 1][row] = v.y;
            As[kq * 4 + 2][row] = v.z; As[kq * 4 + 3][row] = v.w;
        }
        #pragma unroll
        for (int rep = 0; rep < 2; rep++) {
            int fi = t + rep * 256;
            int row = fi >> 2, kq = fi & 3;
            float4 v = make_float4(0.f, 0.f, 0.f, 0.f);
            if (n0 + row < N)
                v = *reinterpret_cast<const float4*>(&W[(long)(n0 + row) * K + k0 + kq * 4]);
            Ws[kq * 4 + 0][row] = v.x; Ws[kq * 4 + 1][row] = v.y;
            Ws[kq * 4 + 2][row] = v.z; Ws[kq * 4 + 3][row] = v.w;
        }
        __syncthreads();
        #pragma unroll
        for (int kk = 0; kk < TKg; kk++) {
            float a8[8], w8[8];
            #pragma unroll
            for (int i = 0; i < 8; i++) a8[i] = As[kk][tm * 8 + i];
            #pragma unroll
            for (int j = 0; j < 8; j++) w8[j] = Ws[kk][tn * 8 + j];
            #pragma unroll
            for (int i = 0; i < 8; i++)
                #pragma unroll
                for (int j = 0; j < 8; j++)
                    acc[i][j] += a8[i] * w8[j];
        }
        __syncthreads();
    }
    #pragma unroll
    for (int i = 0; i < 8; i++) {
        int r = m0 + tm * 8 + i;
        if (r >= M) continue;
        long base;
        if (fc_mode) {
            int b = r / 127, tl = r - b * 127;
            base = (long)(b * S_ + tl + 1) * N;
        } else {
            base = (long)r * N;
        }
        #pragma unroll
        for (int j = 0; j < 8; j++) {
            int c = n0 + tn * 8 + j;
            if (c < N) C[base + c] = acc[i][j] + bias[c];
        }
    }
}

// ---------------- recurrent gates: partial[kc][b][col] = sum_{k in slice} h[b][k]*WhhT[k][col] ----
__global__ __launch_bounds__(256) void lstm_gates_kernel(
    const float* __restrict__ WT,    // [H][G4]  (Whh transposed)
    const float* __restrict__ h,     // [B][H]
    float* __restrict__ partial)     // [4][B][G4]
{
    __shared__ float hs[16][256];
    int cc = blockIdx.x;   // 0..63 col chunk (64 cols)
    int kc = blockIdx.y;   // 0..3  k chunk (256 k)
    int t = threadIdx.x;
    int k0 = kc * 256;
    for (int i = t; i < 16 * 256; i += 256)
        hs[i >> 8][i & 255] = h[(i >> 8) * H_ + k0 + (i & 255)];
    __syncthreads();
    int col = cc * 64 + (t & 63);
    int b0  = (t >> 6) * 4;          // each wave handles 4 batch rows
    float acc0 = 0.f, acc1 = 0.f, acc2 = 0.f, acc3 = 0.f;
    const float* wp = WT + (long)k0 * G4 + col;
    #pragma unroll 4
    for (int kk = 0; kk < 256; kk += 4) {
        float w0 = wp[0];
        float w1 = wp[G4];
        float w2 = wp[2 * G4];
        float w3 = wp[3 * G4];
        wp += 4 * G4;
        float4 ha = *reinterpret_cast<const float4*>(&hs[b0 + 0][kk]);
        float4 hb = *reinterpret_cast<const float4*>(&hs[b0 + 1][kk]);
        float4 hc = *reinterpret_cast<const float4*>(&hs[b0 + 2][kk]);
        float4 hd = *reinterpret_cast<const float4*>(&hs[b0 + 3][kk]);
        acc0 += ha.x * w0 + ha.y * w1 + ha.z * w2 + ha.w * w3;
        acc1 += hb.x * w0 + hb.y * w1 + hb.z * w2 + hb.w * w3;
        acc2 += hc.x * w0 + hc.y * w1 + hc.z * w2 + hc.w * w3;
        acc3 += hd.x * w0 + hd.y * w1 + hd.z * w2 + hd.w * w3;
    }
    float* pp = partial + ((long)kc * 16 + b0) * G4 + col;
    pp[0]      = acc0;
    pp[G4]     = acc1;
    pp[2 * G4] = acc2;
    pp[3 * G4] = acc3;
}

// ---------------- cell update: gates -> (h,c,y) ----------------
__global__ __launch_bounds__(256) void lstm_cell_kernel(
    const float* __restrict__ partial,   // [4][B][G4]
    const float* __restrict__ Xg,        // [B*T][G4]  (x@Wih^T + b, precomputed)
    float* __restrict__ h, float* __restrict__ c,
    float* __restrict__ y,               // [B*T][H] (ignored if write_y==0)
    int tstep, int T, int write_y)
{
    int i = blockIdx.x * 256 + threadIdx.x;   // 0..B*H-1
    int b = i >> 10, j = i & 1023;
    float g0 = 0.f, g1 = 0.f, g2 = 0.f, g3 = 0.f;
    #pragma unroll
    for (int kc = 0; kc < 4; kc++) {
        const float* pp = partial + ((long)kc * 16 + b) * G4 + j;
        g0 += pp[0]; g1 += pp[H_]; g2 += pp[2 * H_]; g3 += pp[3 * H_];
    }
    const float* xg = Xg + ((long)b * T + tstep) * G4 + j;
    g0 += xg[0]; g1 += xg[H_]; g2 += xg[2 * H_]; g3 += xg[3 * H_];
    float ig = 1.f / (1.f + expf(-g0));
    float fg = 1.f / (1.f + expf(-g1));
    float gg = tanhf(g2);
    float og = 1.f / (1.f + expf(-g3));
    float cn = fg * c[i] + ig * gg;
    float hn = og * tanhf(cn);
    c[i] = cn;
    h[i] = hn;
    if (write_y) y[((long)b * T + tstep) * H_ + j] = hn;
}

// ---------------- zero out[:,0,:] ----------------
__global__ __launch_bounds__(256) void zero_first_kernel(float* __restrict__ out)
{
    int i = blockIdx.x * 256 + threadIdx.x;
    if (i < B_ * V_) {
        int b = i / V_, v = i - b * V_;
        out[(long)b * S_ * V_ + v] = 0.f;
    }
}

extern "C" void kernel_launch(void* const* d_in, const int* in_sizes, int n_in,
                              void* d_out, int out_size, void* d_ws, size_t ws_size,
                              hipStream_t stream)
{
    const int*   src     = (const int*)  d_in[0];
    const int*   trg     = (const int*)  d_in[1];
    const float* enc_emb = (const float*)d_in[2];
    const float* dec_emb = (const float*)d_in[3];
    const float* eWih0   = (const float*)d_in[4];
    const float* eWhh0   = (const float*)d_in[5];
    const float* eb0     = (const float*)d_in[6];
    const float* eWih1   = (const float*)d_in[7];
    const float* eWhh1   = (const float*)d_in[8];
    const float* eb1     = (const float*)d_in[9];
    const float* dWih0   = (const float*)d_in[10];
    const float* dWhh0   = (const float*)d_in[11];
    const float* db0     = (const float*)d_in[12];
    const float* dWih1   = (const float*)d_in[13];
    const float* dWhh1   = (const float*)d_in[14];
    const float* db1     = (const float*)d_in[15];
    const float* fcW     = (const float*)d_in[16];
    const float* fcb     = (const float*)d_in[17];
    float* out = (float*)d_out;

    // workspace layout (floats) — buffers reused across strictly-ordered phases.
    // Total 16,056,320 floats = 61.25 MB (was 107 MB; shrunk in case ws_size
    // is smaller than assumed — OOB ws writes could explain container deaths).
    const size_t WS_FLOATS = 4194304ull + 8388608ull + 1048576ull + 2097152ull
                           + 262144ull + 4ull * 16384ull;
    if (ws_size < WS_FLOATS * sizeof(float)) return;  // guard: stub-like absmax 0.586 => ws too small

    float* ws   = (float*)d_ws;
    float* WT   = ws;                  // 1024*4096 = 4,194,304   (per-layer Whh^T)
    float* Xg   = WT   + 4194304;      // 2048*4096 = 8,388,608   (per-layer x@Wih^T+b)
    float* xbuf = Xg   + 8388608;      // 2048*512  = 1,048,576   (embeddings)
    float* ybuf = xbuf + 1048576;      // 2048*1024 = 2,097,152   (layer outputs; decL1 reuses as d1)
    float* part = ybuf + 2097152;      // 4*16*4096 = 262,144
    float* hA   = part + 262144;       // 16*1024 each: hA,cA,hB,cB
    float* cA   = hA + 16384;
    float* hB   = cA + 16384;
    float* cB   = hB + 16384;
    float* d1   = ybuf;                // alias: decL1 outputs overwrite ybuf (dead by then)

    hipMemsetAsync(hA, 0, 4 * 16384 * sizeof(float), stream);   // zero h/c states

    dim3 b256(256);

    // ======== encoder layer 0 ========
    embed_kernel<<<dim3((2048 * (E_/4) + 255) / 256), b256, 0, stream>>>(src, enc_emb, xbuf, 2048, 128, 128);
    gemm_bias_kernel<<<dim3(G4 / TN, 16), b256, 0, stream>>>(xbuf, eWih0, eb0, Xg, 2048, G4, E_, 0);
    transpose_kernel<<<dim3(H_ / 32, G4 / 32), b256, 0, stream>>>(eWhh0, WT, G4, H_);
    for (int tstep = 0; tstep < 128; tstep++) {
        lstm_gates_kernel<<<dim3(64, 4), b256, 0, stream>>>(WT, hA, part);
        lstm_cell_kernel<<<dim3(64), b256, 0, stream>>>(part, Xg, hA, cA, ybuf, tstep, 128, 1);
    }
    // ======== encoder layer 1 (Xg/WT overwritten — L0 scan complete) ========
    gemm_bias_kernel<<<dim3(G4 / TN, 16), b256, 0, stream>>>(ybuf, eWih1, eb1, Xg, 2048, G4, H_, 0);
    transpose_kernel<<<dim3(H_ / 32, G4 / 32), b256, 0, stream>>>(eWhh1, WT, G4, H_);
    for (int tstep = 0; tstep < 128; tstep++) {
        lstm_gates_kernel<<<dim3(64, 4), b256, 0, stream>>>(WT, hB, part);
        lstm_cell_kernel<<<dim3(64), b256, 0, stream>>>(part, Xg, hB, cB, nullptr, tstep, 128, 0);
    }
    // ======== decoder layer 0 (continues hA/cA; ybuf overwritten — encL1 done) ========
    embed_kernel<<<dim3((2032 * (E_/4) + 255) / 256), b256, 0, stream>>>(trg, dec_emb, xbuf, 2032, 127, 128);
    gemm_bias_kernel<<<dim3(G4 / TN, 16), b256, 0, stream>>>(xbuf, dWih0, db0, Xg, 2032, G4, E_, 0);
    transpose_kernel<<<dim3(H_ / 32, G4 / 32), b256, 0, stream>>>(dWhh0, WT, G4, H_);
    for (int tstep = 0; tstep < 127; tstep++) {
        lstm_gates_kernel<<<dim3(64, 4), b256, 0, stream>>>(WT, hA, part);
        lstm_cell_kernel<<<dim3(64), b256, 0, stream>>>(part, Xg, hA, cA, ybuf, tstep, 127, 1);
    }
    // ======== decoder layer 1 (continues hB/cB; d1 aliases ybuf — gemm reads ybuf first) ========
    gemm_bias_kernel<<<dim3(G4 / TN, 16), b256, 0, stream>>>(ybuf, dWih1, db1, Xg, 2032, G4, H_, 0);
    transpose_kernel<<<dim3(H_ / 32, G4 / 32), b256, 0, stream>>>(dWhh1, WT, G4, H_);
    for (int tstep = 0; tstep < 127; tstep++) {
        lstm_gates_kernel<<<dim3(64, 4), b256, 0, stream>>>(WT, hB, part);
        lstm_cell_kernel<<<dim3(64), b256, 0, stream>>>(part, Xg, hB, cB, d1, tstep, 127, 1);
    }
    // ======== output: out[:,0,:]=0 ; out[:,1:,:] = d1 @ fcW^T + fcb ========
    zero_first_kernel<<<dim3((B_ * V_ + 255) / 256), b256, 0, stream>>>(out);
    gemm_bias_kernel<<<dim3(V_ / TN, 16), b256, 0, stream>>>(d1, fcW, fcb, out, 2032, V_, H_, 1);
}